// Round 1
// baseline (381.228 us; speedup 1.0000x reference)
//
#include <hip/hip_runtime.h>

#define B_ 8
#define K_ 8
#define H_ 256
#define W_ 256
#define HW (H_*W_)

// ---------------------------------------------------------------------------
// helpers
// ---------------------------------------------------------------------------
__device__ __forceinline__ double wave_reduce_d(double v) {
    // wavefront = 64 on gfx950
    #pragma unroll
    for (int off = 32; off > 0; off >>= 1) v += __shfl_down(v, off, 64);
    return v;
}

// ---------------------------------------------------------------------------
// Phase A: per-batch 8x8 Gram matrix of dIdp (36 unique entries, double acc)
// grid = B_*64 blocks, 256 threads; 64 blocks per batch
// ---------------------------------------------------------------------------
__global__ __launch_bounds__(256) void gram_kernel(const float* __restrict__ temp,
                                                   double* __restrict__ Hacc) {
    const int b   = blockIdx.x >> 6;
    const int blk = blockIdx.x & 63;
    const int tid = threadIdx.x;

    double acc[36];
    #pragma unroll
    for (int i = 0; i < 36; ++i) acc[i] = 0.0;

    for (int px = blk * 256 + tid; px < HW; px += 64 * 256) {
        const int y = px >> 8, x = px & 255;
        const float X = (float)x - 127.5f;
        const float Y = (float)y - 127.5f;
        const int xm = (x > 0)   ? x - 1 : 0;
        const int xp = (x < 255) ? x + 1 : 255;
        const int ym = (y > 0)   ? y - 1 : 0;
        const int yp = (y < 255) ? y + 1 : 255;
        #pragma unroll
        for (int c = 0; c < K_; ++c) {
            const float* T = temp + (size_t)(b * K_ + c) * HW;
            const float gx = 0.5f * (T[y * W_ + xp] - T[y * W_ + xm]);
            const float gy = 0.5f * (T[yp * W_ + x] - T[ym * W_ + x]);
            float J[8];
            J[0] = X * gx; J[1] = Y * gx; J[2] = gx;
            J[3] = X * gy; J[4] = Y * gy; J[5] = gy;
            J[6] = -X * X * gx - X * Y * gy;
            J[7] = -X * Y * gx - Y * Y * gy;
            double dJ[8];
            #pragma unroll
            for (int i2 = 0; i2 < 8; ++i2) dJ[i2] = (double)J[i2];
            int idx = 0;
            #pragma unroll
            for (int p2 = 0; p2 < 8; ++p2) {
                #pragma unroll
                for (int q2 = p2; q2 < 8; ++q2) {
                    acc[idx++] += dJ[p2] * dJ[q2];
                }
            }
        }
    }

    __shared__ double lds[4][36];
    const int wave = tid >> 6, lane = tid & 63;
    #pragma unroll
    for (int e = 0; e < 36; ++e) {
        double v = wave_reduce_d(acc[e]);
        if (lane == 0) lds[wave][e] = v;
    }
    __syncthreads();
    if (tid < 36) {
        double v = lds[0][tid] + lds[1][tid] + lds[2][tid] + lds[3][tid];
        atomicAdd(&Hacc[b * 36 + tid], v);
    }
}

// ---------------------------------------------------------------------------
// Phase B: invert 8x8 (SPD Gram -> no pivoting needed), double, Gauss-Jordan
// grid = B_ blocks, 64 threads (i = t/8, j = t%8)
// ---------------------------------------------------------------------------
__global__ void invert_kernel(const double* __restrict__ Hacc,
                              double* __restrict__ invH) {
    const int b = blockIdx.x;
    const int t = threadIdx.x;
    const int i = t >> 3, j = t & 7;
    __shared__ double A[64];
    __shared__ double Bi[64];
    const int p2 = min(i, j), q2 = max(i, j);
    const int tri = 8 * p2 - (p2 * (p2 - 1)) / 2 + (q2 - p2);
    A[t]  = Hacc[b * 36 + tri];
    Bi[t] = (i == j) ? 1.0 : 0.0;
    __syncthreads();
    for (int k = 0; k < 8; ++k) {
        const double piv = A[k * 8 + k];
        __syncthreads();
        if (i == k) { A[t] /= piv; Bi[t] /= piv; }
        __syncthreads();
        const double f  = A[i * 8 + k];
        const double ak = A[k * 8 + j];
        const double bk = Bi[k * 8 + j];
        __syncthreads();
        if (i != k) { A[t] -= f * ak; Bi[t] -= f * bk; }
        __syncthreads();
    }
    invH[b * 64 + t] = Bi[t];
}

// ---------------------------------------------------------------------------
// init p (from init_param) and dp = 1
// ---------------------------------------------------------------------------
__global__ void init_kernel(const float* __restrict__ init_param,
                            double* __restrict__ p, double* __restrict__ dp) {
    const int t = threadIdx.x;  // 64
    p[t]  = (double)init_param[t];
    dp[t] = 1.0;
}

// ---------------------------------------------------------------------------
// Phase C1: warp + bilinear sample + residual + s = dIdp^T r  (double acc)
// grid = B_*64 blocks, 256 threads
// ---------------------------------------------------------------------------
__global__ __launch_bounds__(256) void iter_residual_kernel(
    const float* __restrict__ img, const float* __restrict__ temp,
    const double* __restrict__ p, double* __restrict__ s,
    const int* __restrict__ max_itr, int iter) {
    if (iter >= *max_itr) return;
    const int b   = blockIdx.x >> 6;
    const int blk = blockIdx.x & 63;
    const int tid = threadIdx.x;

    const double* pb = p + b * 8;
    const float h00 = 1.f + (float)pb[0], h01 = (float)pb[1], h02 = (float)pb[2];
    const float h10 = (float)pb[3], h11 = 1.f + (float)pb[4], h12 = (float)pb[5];
    const float h20 = (float)pb[6], h21 = (float)pb[7];

    const float XN_LO = -1.f + 2.f / (float)W_;
    const float XN_HI =  1.f - 2.f / (float)W_;
    const float YN_LO = -1.f + 2.f / (float)H_;
    const float YN_HI =  1.f - 2.f / (float)H_;

    double acc[8];
    #pragma unroll
    for (int e = 0; e < 8; ++e) acc[e] = 0.0;

    for (int px = blk * 256 + tid; px < HW; px += 64 * 256) {
        const int y = px >> 8, x = px & 255;
        const float X = (float)x - 127.5f;
        const float Y = (float)y - 127.5f;
        const float xw = h00 * X + h01 * Y + h02;
        const float yw = h10 * X + h11 * Y + h12;
        const float zw = h20 * X + h21 * Y + 1.f;
        const float Xw = xw / zw + 127.5f;
        const float Yw = yw / zw + 127.5f;

        const float xn = Xw / 127.5f - 1.f;
        const float yn = Yw / 127.5f - 1.f;
        const float m = (xn > XN_LO && xn < XN_HI && yn > YN_LO && yn < YN_HI) ? 1.f : 0.f;

        const float x0f = floorf(Xw), y0f = floorf(Yw);
        const float fx = Xw - x0f, fy = Yw - y0f;
        const float x1f = x0f + 1.f, y1f = y0f + 1.f;
        const bool vx0 = (x0f >= 0.f) && (x0f <= 255.f);
        const bool vx1 = (x1f >= 0.f) && (x1f <= 255.f);
        const bool vy0 = (y0f >= 0.f) && (y0f <= 255.f);
        const bool vy1 = (y1f >= 0.f) && (y1f <= 255.f);
        const int xi0 = (int)fminf(fmaxf(x0f, 0.f), 255.f);
        const int xi1 = (int)fminf(fmaxf(x1f, 0.f), 255.f);
        const int yi0 = (int)fminf(fmaxf(y0f, 0.f), 255.f);
        const int yi1 = (int)fminf(fmaxf(y1f, 0.f), 255.f);
        const float f00 = (vx0 && vy0) ? 1.f : 0.f;
        const float f01 = (vx1 && vy0) ? 1.f : 0.f;
        const float f10 = (vx0 && vy1) ? 1.f : 0.f;
        const float f11 = (vx1 && vy1) ? 1.f : 0.f;
        const int i00 = yi0 * W_ + xi0, i01 = yi0 * W_ + xi1;
        const int i10 = yi1 * W_ + xi0, i11 = yi1 * W_ + xi1;
        const float w00 = (1.f - fx) * (1.f - fy);
        const float w01 = fx * (1.f - fy);
        const float w10 = (1.f - fx) * fy;
        const float w11 = fx * fy;

        const int xm = (x > 0)   ? x - 1 : 0;
        const int xp = (x < 255) ? x + 1 : 255;
        const int ym = (y > 0)   ? y - 1 : 0;
        const int yp = (y < 255) ? y + 1 : 255;

        #pragma unroll
        for (int c = 0; c < K_; ++c) {
            const float* A = img  + (size_t)(b * K_ + c) * HW;
            const float* T = temp + (size_t)(b * K_ + c) * HW;
            const float v00 = f00 * A[i00];
            const float v01 = f01 * A[i01];
            const float v10 = f10 * A[i10];
            const float v11 = f11 * A[i11];
            const float Q = w00 * v00 + w01 * v01 + w10 * v10 + w11 * v11;
            const float r = Q - T[px] * m;
            const float gx = 0.5f * (T[y * W_ + xp] - T[y * W_ + xm]);
            const float gy = 0.5f * (T[yp * W_ + x] - T[ym * W_ + x]);
            const float J0 = X * gx, J1 = Y * gx;
            const float J3 = X * gy, J4 = Y * gy;
            const float J6 = -X * X * gx - X * Y * gy;
            const float J7 = -X * Y * gx - Y * Y * gy;
            const double rd = (double)r;
            acc[0] += (double)J0 * rd;
            acc[1] += (double)J1 * rd;
            acc[2] += (double)gx * rd;
            acc[3] += (double)J3 * rd;
            acc[4] += (double)J4 * rd;
            acc[5] += (double)gy * rd;
            acc[6] += (double)J6 * rd;
            acc[7] += (double)J7 * rd;
        }
    }

    __shared__ double lds[4][8];
    const int wave = tid >> 6, lane = tid & 63;
    #pragma unroll
    for (int e = 0; e < 8; ++e) {
        double v = wave_reduce_d(acc[e]);
        if (lane == 0) lds[wave][e] = v;
    }
    __syncthreads();
    if (tid < 8) {
        double v = lds[0][tid] + lds[1][tid] + lds[2][tid] + lds[3][tid];
        atomicAdd(&s[b * 8 + tid], v);
    }
}

// ---------------------------------------------------------------------------
// Phase C2: dp = invH @ s; zero [6:8]; freeze if ||dp_prev|| <= TOL; p -= dp
// 1 block, 64 threads (b = t/8, q = t%8). Also re-zeroes s for next iter.
// ---------------------------------------------------------------------------
__global__ void update_kernel(const double* __restrict__ invH,
                              double* __restrict__ s,
                              double* __restrict__ p, double* __restrict__ dp,
                              const int* __restrict__ max_itr, int iter) {
    if (iter >= *max_itr) return;
    const int t = threadIdx.x;  // 64
    const int b = t >> 3, q = t & 7;
    __shared__ double sh_s[8][8];
    __shared__ double sh_n[8][8];
    sh_s[b][q] = s[t];
    const double d = dp[t];
    sh_n[b][q] = d * d;
    __syncthreads();
    double dpn = 0.0;
    if (q < 6) {
        #pragma unroll
        for (int k = 0; k < 8; ++k) dpn += invH[b * 64 + q * 8 + k] * sh_s[b][k];
    }
    double nrm2 = 0.0;
    #pragma unroll
    for (int k = 0; k < 8; ++k) nrm2 += sh_n[b][k];
    const double active = (sqrt(nrm2) > 1e-3) ? 1.0 : 0.0;
    const double dp2 = active * dpn;
    p[t] -= dp2;
    dp[t] = dp2;
    s[t] = 0.0;
}

// ---------------------------------------------------------------------------
// output: p (64 f32), then H = param_to_H(p) (72 f32)
// ---------------------------------------------------------------------------
__global__ void output_kernel(const double* __restrict__ p, float* __restrict__ out) {
    const int t = threadIdx.x;  // 128
    if (t < 64) out[t] = (float)p[t];
    if (t < 72) {
        const int b = t / 9, j = t % 9;
        float v = (j < 8) ? (float)p[b * 8 + j] : 0.f;
        if (j == 0 || j == 4 || j == 8) v += 1.f;
        out[64 + t] = v;
    }
}

extern "C" void kernel_launch(void* const* d_in, const int* in_sizes, int n_in,
                              void* d_out, int out_size, void* d_ws, size_t ws_size,
                              hipStream_t stream) {
    const float* img        = (const float*)d_in[0];
    const float* temp       = (const float*)d_in[1];
    const float* init_param = (const float*)d_in[2];
    const int*   max_itr    = (const int*)d_in[3];
    float* out = (float*)d_out;

    double* ws   = (double*)d_ws;
    double* Hacc = ws;          // B*36 = 288 doubles
    double* s    = ws + 288;    // B*8  = 64 doubles
    double* invH = ws + 352;    // B*64 = 512 doubles
    double* p    = ws + 864;    // 64 doubles
    double* dp   = ws + 928;    // 64 doubles

    // zero the accumulators (Hacc + s); rest is fully overwritten each call
    hipMemsetAsync(d_ws, 0, 352 * sizeof(double), stream);

    gram_kernel<<<B_ * 64, 256, 0, stream>>>(temp, Hacc);
    invert_kernel<<<B_, 64, 0, stream>>>(Hacc, invH);
    init_kernel<<<1, 64, 0, stream>>>(init_param, p, dp);

    for (int it = 0; it < 10; ++it) {
        iter_residual_kernel<<<B_ * 64, 256, 0, stream>>>(img, temp, p, s, max_itr, it);
        update_kernel<<<1, 64, 0, stream>>>(invH, s, p, dp, max_itr, it);
    }
    output_kernel<<<1, 128, 0, stream>>>(p, out);
}

// Round 2
// 367.857 us; speedup vs baseline: 1.0363x; 1.0363x over previous
//
#include <hip/hip_runtime.h>

#define B_ 8
#define K_ 8
#define H_ 256
#define W_ 256
#define HW (H_*W_)

// ---------------------------------------------------------------------------
// helpers
// ---------------------------------------------------------------------------
__device__ __forceinline__ double wave_reduce_d(double v) {
    #pragma unroll
    for (int off = 32; off > 0; off >>= 1) v += __shfl_down(v, off, 64);
    return v;
}

// ---------------------------------------------------------------------------
// Phase A: per-batch 8x8 Gram matrix (36 unique entries) + store (gx,gy)
// grid = B_*64 blocks, 256 threads; 4 px/thread
// Per-pixel products accumulated in f32 across channels, then f64 per thread.
// ---------------------------------------------------------------------------
__global__ __launch_bounds__(256) void gram_kernel(const float* __restrict__ temp,
                                                   double* __restrict__ Hacc,
                                                   float2* __restrict__ grads) {
    const int b   = blockIdx.x >> 6;
    const int blk = blockIdx.x & 63;
    const int tid = threadIdx.x;

    double acc[36];
    #pragma unroll
    for (int i = 0; i < 36; ++i) acc[i] = 0.0;

    for (int px = blk * 256 + tid; px < HW; px += 64 * 256) {
        const int y = px >> 8, x = px & 255;
        const float X = (float)x - 127.5f;
        const float Y = (float)y - 127.5f;
        const int xm = (x > 0)   ? x - 1 : 0;
        const int xp = (x < 255) ? x + 1 : 255;
        const int ym = (y > 0)   ? y - 1 : 0;
        const int yp = (y < 255) ? y + 1 : 255;

        float facc[36];
        #pragma unroll
        for (int i = 0; i < 36; ++i) facc[i] = 0.f;

        #pragma unroll
        for (int c = 0; c < K_; ++c) {
            const float* T = temp + (size_t)(b * K_ + c) * HW;
            const float gx = 0.5f * (T[y * W_ + xp] - T[y * W_ + xm]);
            const float gy = 0.5f * (T[yp * W_ + x] - T[ym * W_ + x]);
            grads[(size_t)(b * K_ + c) * HW + px] = make_float2(gx, gy);
            float J[8];
            J[0] = X * gx; J[1] = Y * gx; J[2] = gx;
            J[3] = X * gy; J[4] = Y * gy; J[5] = gy;
            J[6] = -X * X * gx - X * Y * gy;
            J[7] = -X * Y * gx - Y * Y * gy;
            int idx = 0;
            #pragma unroll
            for (int p2 = 0; p2 < 8; ++p2)
                #pragma unroll
                for (int q2 = p2; q2 < 8; ++q2)
                    facc[idx++] += J[p2] * J[q2];
        }
        #pragma unroll
        for (int i = 0; i < 36; ++i) acc[i] += (double)facc[i];
    }

    __shared__ double lds[4][36];
    const int wave = tid >> 6, lane = tid & 63;
    #pragma unroll
    for (int e = 0; e < 36; ++e) {
        double v = wave_reduce_d(acc[e]);
        if (lane == 0) lds[wave][e] = v;
    }
    __syncthreads();
    if (tid < 36) {
        double v = lds[0][tid] + lds[1][tid] + lds[2][tid] + lds[3][tid];
        atomicAdd(&Hacc[b * 36 + tid], v);
    }
}

// ---------------------------------------------------------------------------
// Phase B: invert 8x8 Gram (SPD), double Gauss-Jordan. grid=B_, 64 thr
// ---------------------------------------------------------------------------
__global__ void invert_kernel(const double* __restrict__ Hacc,
                              double* __restrict__ invH) {
    const int b = blockIdx.x;
    const int t = threadIdx.x;
    const int i = t >> 3, j = t & 7;
    __shared__ double A[64];
    __shared__ double Bi[64];
    const int p2 = min(i, j), q2 = max(i, j);
    const int tri = 8 * p2 - (p2 * (p2 - 1)) / 2 + (q2 - p2);
    A[t]  = Hacc[b * 36 + tri];
    Bi[t] = (i == j) ? 1.0 : 0.0;
    __syncthreads();
    for (int k = 0; k < 8; ++k) {
        const double piv = A[k * 8 + k];
        __syncthreads();
        if (i == k) { A[t] /= piv; Bi[t] /= piv; }
        __syncthreads();
        const double f  = A[i * 8 + k];
        const double ak = A[k * 8 + j];
        const double bk = Bi[k * 8 + j];
        __syncthreads();
        if (i != k) { A[t] -= f * ak; Bi[t] -= f * bk; }
        __syncthreads();
    }
    invH[b * 64 + t] = Bi[t];
}

// ---------------------------------------------------------------------------
// init p (from init_param) and dp = 1
// ---------------------------------------------------------------------------
__global__ void init_kernel(const float* __restrict__ init_param,
                            double* __restrict__ p, double* __restrict__ dp) {
    const int t = threadIdx.x;  // 64
    p[t]  = (double)init_param[t];
    dp[t] = 1.0;
}

// ---------------------------------------------------------------------------
// Phase C1: warp + bilinear + residual + s-partials.
// grid = B_*256 blocks, 256 threads; exactly 1 pixel/thread.
// f32 per-thread accumulation (8 channels), f64 reduce, per-block partials.
// ---------------------------------------------------------------------------
__global__ __launch_bounds__(256, 4) void iter_residual_kernel(
    const float* __restrict__ img, const float* __restrict__ temp,
    const float2* __restrict__ grads,
    const double* __restrict__ p, double* __restrict__ partials,
    const int* __restrict__ max_itr, int iter) {
    if (iter >= *max_itr) return;
    const int b   = blockIdx.x >> 8;
    const int pix = ((blockIdx.x & 255) << 8) | threadIdx.x;
    const int tid = threadIdx.x;

    const double* pb = p + b * 8;
    const float h00 = 1.f + (float)pb[0], h01 = (float)pb[1], h02 = (float)pb[2];
    const float h10 = (float)pb[3], h11 = 1.f + (float)pb[4], h12 = (float)pb[5];
    const float h20 = (float)pb[6], h21 = (float)pb[7];

    const float XN_LO = -1.f + 2.f / (float)W_;
    const float XN_HI =  1.f - 2.f / (float)W_;
    const float YN_LO = -1.f + 2.f / (float)H_;
    const float YN_HI =  1.f - 2.f / (float)H_;

    const int y = pix >> 8, x = pix & 255;
    const float X = (float)x - 127.5f;
    const float Y = (float)y - 127.5f;
    const float xw = h00 * X + h01 * Y + h02;
    const float yw = h10 * X + h11 * Y + h12;
    const float zw = h20 * X + h21 * Y + 1.f;
    const float Xw = xw / zw + 127.5f;
    const float Yw = yw / zw + 127.5f;

    const float xn = Xw / 127.5f - 1.f;
    const float yn = Yw / 127.5f - 1.f;
    const float m = (xn > XN_LO && xn < XN_HI && yn > YN_LO && yn < YN_HI) ? 1.f : 0.f;

    const float x0f = floorf(Xw), y0f = floorf(Yw);
    const float fx = Xw - x0f, fy = Yw - y0f;
    const float x1f = x0f + 1.f, y1f = y0f + 1.f;
    const bool vx0 = (x0f >= 0.f) && (x0f <= 255.f);
    const bool vx1 = (x1f >= 0.f) && (x1f <= 255.f);
    const bool vy0 = (y0f >= 0.f) && (y0f <= 255.f);
    const bool vy1 = (y1f >= 0.f) && (y1f <= 255.f);
    const int xi0 = (int)fminf(fmaxf(x0f, 0.f), 255.f);
    const int xi1 = (int)fminf(fmaxf(x1f, 0.f), 255.f);
    const int yi0 = (int)fminf(fmaxf(y0f, 0.f), 255.f);
    const int yi1 = (int)fminf(fmaxf(y1f, 0.f), 255.f);
    const int i00 = yi0 * W_ + xi0, i01 = yi0 * W_ + xi1;
    const int i10 = yi1 * W_ + xi0, i11 = yi1 * W_ + xi1;
    // fold validity flags into the bilinear weights (once per pixel)
    const float w00 = ((vx0 && vy0) ? 1.f : 0.f) * (1.f - fx) * (1.f - fy);
    const float w01 = ((vx1 && vy0) ? 1.f : 0.f) * fx * (1.f - fy);
    const float w10 = ((vx0 && vy1) ? 1.f : 0.f) * (1.f - fx) * fy;
    const float w11 = ((vx1 && vy1) ? 1.f : 0.f) * fx * fy;

    float a0 = 0.f, a1 = 0.f, a2 = 0.f, a3 = 0.f,
          a4 = 0.f, a5 = 0.f, a6 = 0.f, a7 = 0.f;

    #pragma unroll
    for (int c = 0; c < K_; ++c) {
        const size_t base = (size_t)(b * K_ + c) * HW;
        const float2 g = grads[base + pix];
        const float Tv = temp[base + pix];
        const float* A = img + base;
        const float Q = w00 * A[i00] + w01 * A[i01] + w10 * A[i10] + w11 * A[i11];
        const float r = Q - Tv * m;
        const float ga = g.x * r;
        const float gb = g.y * r;
        const float t0 = X * ga;
        const float t1 = Y * gb;
        const float cc = t0 + t1;
        a0 += t0;       a1 += Y * ga;  a2 += ga;
        a3 += X * gb;   a4 += t1;      a5 += gb;
        a6 -= X * cc;   a7 -= Y * cc;
    }

    __shared__ double lds[4][8];
    const int wave = tid >> 6, lane = tid & 63;
    float accs[8] = {a0, a1, a2, a3, a4, a5, a6, a7};
    #pragma unroll
    for (int e = 0; e < 8; ++e) {
        double v = wave_reduce_d((double)accs[e]);
        if (lane == 0) lds[wave][e] = v;
    }
    __syncthreads();
    if (tid < 8) {
        partials[(size_t)blockIdx.x * 8 + tid] =
            lds[0][tid] + lds[1][tid] + lds[2][tid] + lds[3][tid];
    }
}

// ---------------------------------------------------------------------------
// Phase C2: reduce partials -> s; dp = invH @ s; zero [6:8]; freeze; p -= dp
// grid = B_ blocks, 256 threads.
// ---------------------------------------------------------------------------
__global__ void update_kernel(const double* __restrict__ invH,
                              const double* __restrict__ partials,
                              double* __restrict__ p, double* __restrict__ dp,
                              const int* __restrict__ max_itr, int iter) {
    if (iter >= *max_itr) return;
    const int b = blockIdx.x;
    const int t = threadIdx.x;
    const int e = t & 7, g = t >> 3;  // g in 0..31
    double v = 0.0;
    #pragma unroll
    for (int j = 0; j < 8; ++j)
        v += partials[(size_t)(b * 256 + g * 8 + j) * 8 + e];
    __shared__ double lds[32][8];
    __shared__ double s[8];
    lds[g][e] = v;
    __syncthreads();
    if (t < 8) {
        double sv = 0.0;
        #pragma unroll
        for (int g2 = 0; g2 < 32; ++g2) sv += lds[g2][t];
        s[t] = sv;
    }
    __syncthreads();
    if (t < 8) {
        double nrm2 = 0.0;
        #pragma unroll
        for (int k = 0; k < 8; ++k) { const double d = dp[b * 8 + k]; nrm2 += d * d; }
        double dpn = 0.0;
        if (t < 6) {
            #pragma unroll
            for (int k = 0; k < 8; ++k) dpn += invH[b * 64 + t * 8 + k] * s[k];
        }
        const double active = (sqrt(nrm2) > 1e-3) ? 1.0 : 0.0;
        const double dp2 = active * dpn;
        p[b * 8 + t] -= dp2;   // wave-lockstep: reads of dp above precede this write
        dp[b * 8 + t] = dp2;
    }
}

// ---------------------------------------------------------------------------
// output: p (64 f32), then H = param_to_H(p) (72 f32)
// ---------------------------------------------------------------------------
__global__ void output_kernel(const double* __restrict__ p, float* __restrict__ out) {
    const int t = threadIdx.x;  // 128
    if (t < 64) out[t] = (float)p[t];
    if (t < 72) {
        const int b = t / 9, j = t % 9;
        float v = (j < 8) ? (float)p[b * 8 + j] : 0.f;
        if (j == 0 || j == 4 || j == 8) v += 1.f;
        out[64 + t] = v;
    }
}

extern "C" void kernel_launch(void* const* d_in, const int* in_sizes, int n_in,
                              void* d_out, int out_size, void* d_ws, size_t ws_size,
                              hipStream_t stream) {
    const float* img        = (const float*)d_in[0];
    const float* temp       = (const float*)d_in[1];
    const float* init_param = (const float*)d_in[2];
    const int*   max_itr    = (const int*)d_in[3];
    float* out = (float*)d_out;

    double* ws       = (double*)d_ws;
    double* Hacc     = ws;            // 288 doubles
    double* invH     = ws + 288;      // 512 doubles
    double* p        = ws + 800;      // 64 doubles
    double* dp       = ws + 864;      // 64 doubles
    double* partials = ws + 928;      // 2048*8 = 16384 doubles
    float2* grads    = (float2*)(ws + 17312);  // B*K*HW float2 = 33.5 MB

    hipMemsetAsync(Hacc, 0, 288 * sizeof(double), stream);

    gram_kernel<<<B_ * 64, 256, 0, stream>>>(temp, Hacc, grads);
    invert_kernel<<<B_, 64, 0, stream>>>(Hacc, invH);
    init_kernel<<<1, 64, 0, stream>>>(init_param, p, dp);

    for (int it = 0; it < 10; ++it) {
        iter_residual_kernel<<<B_ * 256, 256, 0, stream>>>(img, temp, grads, p,
                                                           partials, max_itr, it);
        update_kernel<<<B_, 256, 0, stream>>>(invH, partials, p, dp, max_itr, it);
    }
    output_kernel<<<1, 128, 0, stream>>>(p, out);
}